// Round 1
// baseline (1208.633 us; speedup 1.0000x reference)
//
#include <hip/hip_runtime.h>
#include <hip/hip_bf16.h>
#include <math.h>

// StyleGAN3 SynthesisLayer forward, MI355X.
// B=16, CIN=COUT=256, H=W=64, K=3, up=2 down=2 taps=12, conv out 66x66,
// up-FIR out 138x138, final out 64x64.

typedef __attribute__((ext_vector_type(8))) short bf16x8;
typedef __attribute__((ext_vector_type(4))) float f32x4;

#define NM 69696         // 16*66*66 flattened conv-output positions
#define SPI 4356         // 66*66 spatial per image

__device__ inline void gload16(const void* g, void* l) {
  __builtin_amdgcn_global_load_lds((const __attribute__((address_space(1))) void*)g,
                                   (__attribute__((address_space(3))) void*)l, 16, 0, 0);
}

// ---------- styles = w @ aw^T / sqrt(512) + ab ----------
__global__ __launch_bounds__(256) void k_styles(
    const float* __restrict__ w, const float* __restrict__ aw,
    const float* __restrict__ ab, float* __restrict__ styles) {
  __shared__ float lw[512];
  int b = blockIdx.x, t = threadIdx.x;
  lw[t] = w[b * 512 + t];
  lw[t + 256] = w[b * 512 + t + 256];
  __syncthreads();
  const float* row = aw + (long)t * 512;
  float acc = 0.f;
  #pragma unroll 4
  for (int d = 0; d < 512; ++d) acc += row[d] * lw[d];
  styles[b * 256 + t] = acc * 0.04419417382415922f + ab[t];
}

// ---------- scal[0] = 1/mean(styles^2), scal[1] = rsqrt(ema) ----------
__global__ __launch_bounds__(256) void k_scalars(
    const float* __restrict__ styles, const float* __restrict__ ema,
    float* __restrict__ scal) {
  __shared__ float red[256];
  int t = threadIdx.x;
  float s = 0.f;
  #pragma unroll
  for (int k = 0; k < 16; ++k) { float v = styles[t + k * 256]; s += v * v; }
  red[t] = s; __syncthreads();
  for (int off = 128; off > 0; off >>= 1) {
    if (t < off) red[t] += red[t + off];
    __syncthreads();
  }
  if (t == 0) { scal[0] = 4096.0f / red[0]; scal[1] = 1.0f / sqrtf(ema[0]); }
}

// ---------- per-o weight norm; wsq[o][i]; wbt[tap][o][i] bf16 ----------
__global__ __launch_bounds__(256) void k_wnorm(
    const float* __restrict__ cw, float* __restrict__ wsq,
    __hip_bfloat16* __restrict__ wbt) {
  __shared__ float red[256];
  __shared__ float lws, lws2;
  int o = blockIdx.x, t = threadIdx.x;
  const float* base = cw + o * 2304;
  float s = 0.f;
  #pragma unroll
  for (int k = 0; k < 9; ++k) { float v = base[t + k * 256]; s += v * v; }
  red[t] = s; __syncthreads();
  for (int off = 128; off > 0; off >>= 1) {
    if (t < off) red[t] += red[t + off];
    __syncthreads();
  }
  if (t == 0) { lws2 = 2304.0f / red[0]; lws = sqrtf(lws2); }
  __syncthreads();
  const float* r9 = base + t * 9;
  float s9 = 0.f;
  #pragma unroll
  for (int k = 0; k < 9; ++k) s9 += r9[k] * r9[k];
  wsq[o * 256 + t] = lws2 * s9;
  #pragma unroll
  for (int tap = 0; tap < 9; ++tap)
    wbt[(tap * 256 + o) * 256 + t] = __float2bfloat16(r9[tap] * lws);
}

// ---------- dcoefs[b][o] = rsqrt(sum_i s^2 * wsq + 1e-8) * input_gain ----------
__global__ __launch_bounds__(256) void k_dcoefs(
    const float* __restrict__ styles, const float* __restrict__ wsq,
    const float* __restrict__ scal, float* __restrict__ dco) {
  __shared__ float sn2[256];
  int b = blockIdx.x, t = threadIdx.x;
  float v = styles[b * 256 + t];
  sn2[t] = v * v * scal[0];
  __syncthreads();
  const float* wr = wsq + t * 256;
  float acc = 0.f;
  #pragma unroll 4
  for (int i = 0; i < 256; ++i) acc += sn2[i] * wr[i];
  dco[b * 256 + t] = (1.0f / sqrtf(acc + 1e-8f)) * scal[1];
}

// ---------- xs_pad[b][68][68][256] bf16, NHWC, style-scaled, 2px zero border ----------
__global__ __launch_bounds__(256) void k_xpad(
    const float* __restrict__ x, const float* __restrict__ styles,
    const float* __restrict__ scal, unsigned short* __restrict__ xp) {
  __shared__ float lx[64 * 65];
  __shared__ float sc[64];
  int ig = blockIdx.x, hp = blockIdx.y, b = blockIdx.z, t = threadIdx.x;
  int i0 = ig * 64;
  float ss = sqrtf(scal[0]);
  if (t < 64) sc[t] = styles[b * 256 + i0 + t] * ss;
  int h = hp - 2;
  bool inh = (hp >= 2) && (hp < 66);
  if (inh) {
    #pragma unroll
    for (int p = 0; p < 16; ++p) {
      int idx = p * 256 + t; int i = idx >> 6, w = idx & 63;
      lx[i * 65 + w] = x[((b * 256 + i0 + i) * 64 + h) * 64 + w];
    }
  }
  __syncthreads();
  unsigned short* dst = xp + ((long)(b * 68 + hp) * 68) * 256 + i0;
  #pragma unroll
  for (int p = 0; p < 17; ++p) {
    int idx = p * 256 + t; int wp = idx >> 6, i = idx & 63;
    float v = 0.f;
    if (inh && wp >= 2 && wp < 66) v = lx[i * 65 + (wp - 2)] * sc[i];
    __hip_bfloat16 bv = __float2bfloat16(v);
    dst[wp * 256 + i] = *(unsigned short*)&bv;
  }
}

// ---------- conv: implicit GEMM, M=69696 N=256 K=2304, bf16 MFMA 16x16x32 ----------
// Tile BM=128 BN=128 BK=64; grid (2, 545); 256 threads = 4 waves (2x2 of 64x64).
// LDS tiles [row][8 chunks of 16B] with XOR swizzle (chunk ^= row&7), fed by
// global_load_lds w/ pre-swizzled per-lane source. Epilogue scales by
// dcoefs*input_gain + bias and LDS-transposes to write y in NCHW.
__global__ __launch_bounds__(256) void k_conv(
    const unsigned short* __restrict__ xp, const unsigned short* __restrict__ wbt,
    const float* __restrict__ dco, const float* __restrict__ bias,
    float* __restrict__ y) {
  __shared__ __align__(16) unsigned short As[128 * 64];
  __shared__ __align__(16) unsigned short Bs[128 * 64];
  const int t = threadIdx.x;
  const int lane = t & 63;
  const int wave = t >> 6;
  const int wm = wave >> 1, wn = wave & 1;
  const int o0 = blockIdx.x * 128;
  const int m0 = blockIdx.y * 128;

  int abase[4], bbase[4];
  #pragma unroll
  for (int j = 0; j < 4; ++j) {
    int task = j * 256 + t;
    int lm = task >> 3, ch = task & 7;
    int csrc = ch ^ (lm & 7);
    int m = m0 + lm; if (m > NM - 1) m = NM - 1;
    int b = m / SPI; int sp = m - b * SPI;
    int r = sp / 66; int c = sp - r * 66;
    abase[j] = (((b * 68 + r) * 68 + c) << 9) + (csrc << 4);   // bytes
    bbase[j] = ((o0 + lm) << 9) + (csrc << 4);                 // bytes
  }
  f32x4 acc[4][4] = {};
  const char* xb = (const char*)xp;
  const char* wb = (const char*)wbt;
  char* asb = (char*)As;
  char* bsb = (char*)Bs;

  for (int kk = 0; kk < 36; ++kk) {
    int tap = kk >> 2;
    int ch0b = (kk & 3) << 7;            // ch0 * 2 bytes
    int ky = tap / 3, kx = tap - ky * 3;
    int aoff = ((ky * 68 + kx) << 9) + ch0b;
    int boff = (tap << 17) + ch0b;
    #pragma unroll
    for (int j = 0; j < 4; ++j) {
      gload16(xb + abase[j] + aoff, asb + ((j * 256 + t) << 4));
      gload16(wb + bbase[j] + boff, bsb + ((j * 256 + t) << 4));
    }
    __syncthreads();   // drains vmcnt -> tiles visible
    #pragma unroll
    for (int h = 0; h < 2; ++h) {
      bf16x8 av[4], bv[4];
      #pragma unroll
      for (int fm = 0; fm < 4; ++fm) {
        int arow = wm * 64 + fm * 16 + (lane & 15);
        int chk = ((h << 2) + (lane >> 4)) ^ (arow & 7);
        av[fm] = *(const bf16x8*)(asb + arow * 128 + chk * 16);
      }
      #pragma unroll
      for (int fn = 0; fn < 4; ++fn) {
        int brow = wn * 64 + fn * 16 + (lane & 15);
        int chk = ((h << 2) + (lane >> 4)) ^ (brow & 7);
        bv[fn] = *(const bf16x8*)(bsb + brow * 128 + chk * 16);
      }
      #pragma unroll
      for (int fm = 0; fm < 4; ++fm)
        #pragma unroll
        for (int fn = 0; fn < 4; ++fn)
          acc[fm][fn] = __builtin_amdgcn_mfma_f32_16x16x32_bf16(
              av[fm], bv[fn], acc[fm][fn], 0, 0, 0);
    }
    __syncthreads();   // readers done before next overwrite
  }

  // Epilogue: scale + bias, transpose via LDS slab [128m][17], write NCHW.
  float* slab = (float*)As;
  #pragma unroll
  for (int s = 0; s < 8; ++s) {
    if (wn == (s >> 2)) {
      const int sfn = s & 3;
      int ocol = lane & 15;
      int og = o0 + s * 16 + ocol;
      float bo = bias[og];
      #pragma unroll
      for (int fm = 0; fm < 4; ++fm) {
        #pragma unroll
        for (int j = 0; j < 4; ++j) {
          int lm = wm * 64 + fm * 16 + ((lane >> 4) << 2) + j;
          int m = m0 + lm;
          float v = acc[fm][sfn][j];
          if (m < NM) {
            int b = m / SPI;
            v = v * dco[b * 256 + og] + bo;
          }
          slab[lm * 17 + ocol] = v;
        }
      }
    }
    __syncthreads();
    int oc2 = t >> 4;
    int og2 = o0 + s * 16 + oc2;
    #pragma unroll
    for (int p = 0; p < 8; ++p) {
      int lm = (t & 15) + p * 16;
      int m = m0 + lm;
      if (m < NM) {
        int b = m / SPI; int sp = m - b * SPI;
        y[(long)(b * 256 + og2) * SPI + sp] = slab[lm * 17 + oc2];
      }
    }
    __syncthreads();
  }
}

// ---------- filtered_lrelu: one (b,o) 66x66 image per block, all in LDS ----------
struct Filt { float f[12]; };

__global__ __launch_bounds__(256) void k_lrelu(
    const float* __restrict__ y, float* __restrict__ out, Filt ft) {
  extern __shared__ float sm[];
  float* bufY = sm;             // 4356 f32
  float* t1 = sm + 4356;        // 9108 f32   [138][66]
  float* t2 = sm + 13464;       // 19044 f32  [138][138]
  float* t3 = sm;               // 8832 f32   [64][138] overlays bufY (+t1 head)
  const int t = threadIdx.x;
  const long img = blockIdx.x;
  const float* ysrc = y + img * SPI;

  #pragma unroll
  for (int p = 0; p < 5; ++p) {
    int idx = p * 256 + t;
    if (idx < 1089) ((float4*)bufY)[idx] = ((const float4*)ysrc)[idx];
  }
  __syncthreads();
  // vertical up-FIR (6 live taps of 12; zero-stuffed upsample), gain sqrt(4)=2
  for (int p = 0; p < 36; ++p) {
    int e = p * 256 + t;
    if (e < 9108) {
      int rr = e / 66, c = e - rr * 66;
      int p0 = (rr + 1) & 1;
      int yr0 = (rr + p0 - 9) >> 1;   // even value, arithmetic shift exact
      float a = 0.f;
      #pragma unroll
      for (int u = 0; u < 6; ++u) {
        int yr = yr0 + u;
        float cf = p0 ? ft.f[2 * u + 1] : ft.f[2 * u];
        if (yr >= 0 && yr < 66) a += cf * bufY[yr * 66 + c];
      }
      t1[e] = 2.f * a;
    }
  }
  __syncthreads();
  // horizontal up-FIR + lrelu*sqrt(2) + clamp
  for (int p = 0; p < 75; ++p) {
    int e = p * 256 + t;
    if (e < 19044) {
      int rr = e / 138, cc = e - rr * 138;
      int q0 = (cc + 1) & 1;
      int x0 = (cc + q0 - 9) >> 1;
      const float* trow = t1 + rr * 66;
      float a = 0.f;
      #pragma unroll
      for (int u = 0; u < 6; ++u) {
        int xc = x0 + u;
        float cf = q0 ? ft.f[2 * u + 1] : ft.f[2 * u];
        if (xc >= 0 && xc < 66) a += cf * trow[xc];
      }
      a *= 2.f;
      a = (a < 0.f ? 0.2f * a : a) * 1.41421356237f;
      a = fminf(fmaxf(a, -256.f), 256.f);
      t2[e] = a;
    }
  }
  __syncthreads();
  // vertical down-FIR (stride 2, all 12 taps, gain 1)
  for (int p = 0; p < 35; ++p) {
    int e = p * 256 + t;
    if (e < 8832) {
      int pp = e / 138, cc = e - pp * 138;
      const float* col = t2 + (2 * pp) * 138 + cc;
      float a = 0.f;
      #pragma unroll
      for (int j = 0; j < 12; ++j) a += ft.f[j] * col[j * 138];
      t3[e] = a;
    }
  }
  __syncthreads();
  // horizontal down-FIR + store
  for (int p = 0; p < 16; ++p) {
    int ee = p * 256 + t;
    int pp = ee >> 6, q = ee & 63;
    const float* row = t3 + pp * 138 + 2 * q;
    float a = 0.f;
    #pragma unroll
    for (int j = 0; j < 12; ++j) a += ft.f[j] * row[j];
    out[img * 4096 + ee] = a;
  }
}

// ---------- host ----------
static double bessel_i0(double x) {
  double q = x * x * 0.25, term = 1.0, sum = 1.0;
  for (int k = 1; k < 64; ++k) {
    term *= q / ((double)k * (double)k);
    sum += term;
    if (term < sum * 1e-18) break;
  }
  return sum;
}

extern "C" void kernel_launch(void* const* d_in, const int* in_sizes, int n_in,
                              void* d_out, int out_size, void* d_ws, size_t ws_size,
                              hipStream_t stream) {
  const float* x   = (const float*)d_in[0];
  const float* w   = (const float*)d_in[1];
  const float* aw  = (const float*)d_in[2];
  const float* ab  = (const float*)d_in[3];
  const float* cw  = (const float*)d_in[4];
  const float* cb  = (const float*)d_in[5];
  const float* ema = (const float*)d_in[6];
  float* out = (float*)d_out;
  char* ws = (char*)d_ws;

  float* styles        = (float*)(ws + 0);          // 16 KB
  float* scal          = (float*)(ws + 16384);      // 16 B
  float* wsq           = (float*)(ws + 16640);      // 256 KB
  float* dco           = (float*)(ws + 278784);     // 16 KB
  __hip_bfloat16* wbt  = (__hip_bfloat16*)(ws + 295168);   // 1.18 MB  [9][256][256]
  unsigned short* xp   = (unsigned short*)(ws + 1474816);  // 37.9 MB  [16][68][68][256]
  float* y             = (float*)(ws + 39354624);   // 71.4 MB  [16][256][66][66]

  // firwin(12, 16, width=32, fs=128) with Kaiser window (double precision)
  Filt ft;
  {
    double atten = 2.285 * 11.0 * M_PI * 0.5 + 7.95;
    double beta;
    if (atten > 50.0) beta = 0.1102 * (atten - 8.7);
    else if (atten > 21.0) beta = 0.5842 * pow(atten - 21.0, 0.4) + 0.07886 * (atten - 21.0);
    else beta = 0.0;
    double i0b = bessel_i0(beta);
    double h[12], ssum = 0.0;
    for (int n = 0; n < 12; ++n) {
      double xx = ((double)n - 5.5) / 5.5;
      double win = bessel_i0(beta * sqrt(1.0 - xx * xx)) / i0b;
      double mm = ((double)n - 5.5) * 0.25;
      double snc = sin(M_PI * mm) / (M_PI * mm);
      h[n] = 0.25 * snc * win;
      ssum += h[n];
    }
    for (int n = 0; n < 12; ++n) ft.f[n] = (float)(h[n] / ssum);
  }

  k_styles <<<16, 256, 0, stream>>>(w, aw, ab, styles);
  k_scalars<<<1, 256, 0, stream>>>(styles, ema, scal);
  k_wnorm  <<<256, 256, 0, stream>>>(cw, wsq, wbt);
  k_dcoefs <<<16, 256, 0, stream>>>(styles, wsq, scal, dco);
  k_xpad   <<<dim3(4, 68, 16), 256, 0, stream>>>(x, styles, scal, xp);
  k_conv   <<<dim3(2, 545), 256, 0, stream>>>(xp, (const unsigned short*)wbt, dco, cb, y);
  hipFuncSetAttribute((const void*)k_lrelu, hipFuncAttributeMaxDynamicSharedMemorySize, 131072);
  k_lrelu  <<<4096, 256, 130048, stream>>>(y, out, ft);
}

// Round 2
// 414.719 us; speedup vs baseline: 2.9143x; 2.9143x over previous
//
#include <hip/hip_runtime.h>
#include <hip/hip_bf16.h>
#include <math.h>

// StyleGAN3 SynthesisLayer forward, MI355X.
// B=16, CIN=COUT=256, H=W=64, K=3, up=2 down=2 taps=12, conv out 66x66,
// up-FIR out 138x138, final out 64x64.

typedef __attribute__((ext_vector_type(8))) short bf16x8;
typedef __attribute__((ext_vector_type(4))) float f32x4;

#define NM 69696         // 16*66*66 flattened conv-output positions
#define SPI 4356         // 66*66 spatial per image

__device__ inline void gload16(const void* g, void* l) {
  __builtin_amdgcn_global_load_lds((const __attribute__((address_space(1))) void*)g,
                                   (__attribute__((address_space(3))) void*)l, 16, 0, 0);
}

// ---------- styles = w @ aw^T / sqrt(512) + ab ----------
__global__ __launch_bounds__(256) void k_styles(
    const float* __restrict__ w, const float* __restrict__ aw,
    const float* __restrict__ ab, float* __restrict__ styles) {
  __shared__ float lw[512];
  int b = blockIdx.x, t = threadIdx.x;
  lw[t] = w[b * 512 + t];
  lw[t + 256] = w[b * 512 + t + 256];
  __syncthreads();
  const float* row = aw + (long)t * 512;
  float acc = 0.f;
  #pragma unroll 4
  for (int d = 0; d < 512; ++d) acc += row[d] * lw[d];
  styles[b * 256 + t] = acc * 0.04419417382415922f + ab[t];
}

// ---------- scal[0] = 1/mean(styles^2), scal[1] = rsqrt(ema) ----------
__global__ __launch_bounds__(256) void k_scalars(
    const float* __restrict__ styles, const float* __restrict__ ema,
    float* __restrict__ scal) {
  __shared__ float red[256];
  int t = threadIdx.x;
  float s = 0.f;
  #pragma unroll
  for (int k = 0; k < 16; ++k) { float v = styles[t + k * 256]; s += v * v; }
  red[t] = s; __syncthreads();
  for (int off = 128; off > 0; off >>= 1) {
    if (t < off) red[t] += red[t + off];
    __syncthreads();
  }
  if (t == 0) { scal[0] = 4096.0f / red[0]; scal[1] = 1.0f / sqrtf(ema[0]); }
}

// ---------- per-o weight norm; wsq[o][i]; wbt[tap][o][i] bf16 ----------
__global__ __launch_bounds__(256) void k_wnorm(
    const float* __restrict__ cw, float* __restrict__ wsq,
    __hip_bfloat16* __restrict__ wbt) {
  __shared__ float red[256];
  __shared__ float lws, lws2;
  int o = blockIdx.x, t = threadIdx.x;
  const float* base = cw + o * 2304;
  float s = 0.f;
  #pragma unroll
  for (int k = 0; k < 9; ++k) { float v = base[t + k * 256]; s += v * v; }
  red[t] = s; __syncthreads();
  for (int off = 128; off > 0; off >>= 1) {
    if (t < off) red[t] += red[t + off];
    __syncthreads();
  }
  if (t == 0) { lws2 = 2304.0f / red[0]; lws = sqrtf(lws2); }
  __syncthreads();
  const float* r9 = base + t * 9;
  float s9 = 0.f;
  #pragma unroll
  for (int k = 0; k < 9; ++k) s9 += r9[k] * r9[k];
  wsq[o * 256 + t] = lws2 * s9;
  #pragma unroll
  for (int tap = 0; tap < 9; ++tap)
    wbt[(tap * 256 + o) * 256 + t] = __float2bfloat16(r9[tap] * lws);
}

// ---------- dcoefs[b][o] = rsqrt(sum_i s^2 * wsq + 1e-8) * input_gain ----------
__global__ __launch_bounds__(256) void k_dcoefs(
    const float* __restrict__ styles, const float* __restrict__ wsq,
    const float* __restrict__ scal, float* __restrict__ dco) {
  __shared__ float sn2[256];
  int b = blockIdx.x, t = threadIdx.x;
  float v = styles[b * 256 + t];
  sn2[t] = v * v * scal[0];
  __syncthreads();
  const float* wr = wsq + t * 256;
  float acc = 0.f;
  #pragma unroll 4
  for (int i = 0; i < 256; ++i) acc += sn2[i] * wr[i];
  dco[b * 256 + t] = (1.0f / sqrtf(acc + 1e-8f)) * scal[1];
}

// ---------- xs_pad[b][68][68][256] bf16, NHWC, style-scaled, 2px zero border ----------
__global__ __launch_bounds__(256) void k_xpad(
    const float* __restrict__ x, const float* __restrict__ styles,
    const float* __restrict__ scal, unsigned short* __restrict__ xp) {
  __shared__ float lx[64 * 65];
  __shared__ float sc[64];
  int ig = blockIdx.x, hp = blockIdx.y, b = blockIdx.z, t = threadIdx.x;
  int i0 = ig * 64;
  float ss = sqrtf(scal[0]);
  if (t < 64) sc[t] = styles[b * 256 + i0 + t] * ss;
  int h = hp - 2;
  bool inh = (hp >= 2) && (hp < 66);
  if (inh) {
    #pragma unroll
    for (int p = 0; p < 16; ++p) {
      int idx = p * 256 + t; int i = idx >> 6, w = idx & 63;
      lx[i * 65 + w] = x[((b * 256 + i0 + i) * 64 + h) * 64 + w];
    }
  }
  __syncthreads();
  unsigned short* dst = xp + ((long)(b * 68 + hp) * 68) * 256 + i0;
  #pragma unroll
  for (int p = 0; p < 17; ++p) {
    int idx = p * 256 + t; int wp = idx >> 6, i = idx & 63;
    float v = 0.f;
    if (inh && wp >= 2 && wp < 66) v = lx[i * 65 + (wp - 2)] * sc[i];
    __hip_bfloat16 bv = __float2bfloat16(v);
    dst[wp * 256 + i] = *(unsigned short*)&bv;
  }
}

// ---------- conv: implicit GEMM, M=69696 N=256 K=2304, bf16 MFMA 16x16x32 ----------
__global__ __launch_bounds__(256) void k_conv(
    const unsigned short* __restrict__ xp, const unsigned short* __restrict__ wbt,
    const float* __restrict__ dco, const float* __restrict__ bias,
    float* __restrict__ y) {
  __shared__ __align__(16) unsigned short As[128 * 64];
  __shared__ __align__(16) unsigned short Bs[128 * 64];
  const int t = threadIdx.x;
  const int lane = t & 63;
  const int wave = t >> 6;
  const int wm = wave >> 1, wn = wave & 1;
  const int o0 = blockIdx.x * 128;
  const int m0 = blockIdx.y * 128;

  int abase[4], bbase[4];
  #pragma unroll
  for (int j = 0; j < 4; ++j) {
    int task = j * 256 + t;
    int lm = task >> 3, ch = task & 7;
    int csrc = ch ^ (lm & 7);
    int m = m0 + lm; if (m > NM - 1) m = NM - 1;
    int b = m / SPI; int sp = m - b * SPI;
    int r = sp / 66; int c = sp - r * 66;
    abase[j] = (((b * 68 + r) * 68 + c) << 9) + (csrc << 4);   // bytes
    bbase[j] = ((o0 + lm) << 9) + (csrc << 4);                 // bytes
  }
  f32x4 acc[4][4] = {};
  const char* xb = (const char*)xp;
  const char* wb = (const char*)wbt;
  char* asb = (char*)As;
  char* bsb = (char*)Bs;

  for (int kk = 0; kk < 36; ++kk) {
    int tap = kk >> 2;
    int ch0b = (kk & 3) << 7;            // ch0 * 2 bytes
    int ky = tap / 3, kx = tap - ky * 3;
    int aoff = ((ky * 68 + kx) << 9) + ch0b;
    int boff = (tap << 17) + ch0b;
    #pragma unroll
    for (int j = 0; j < 4; ++j) {
      gload16(xb + abase[j] + aoff, asb + ((j * 256 + t) << 4));
      gload16(wb + bbase[j] + boff, bsb + ((j * 256 + t) << 4));
    }
    __syncthreads();   // drains vmcnt -> tiles visible
    #pragma unroll
    for (int h = 0; h < 2; ++h) {
      bf16x8 av[4], bv[4];
      #pragma unroll
      for (int fm = 0; fm < 4; ++fm) {
        int arow = wm * 64 + fm * 16 + (lane & 15);
        int chk = ((h << 2) + (lane >> 4)) ^ (arow & 7);
        av[fm] = *(const bf16x8*)(asb + arow * 128 + chk * 16);
      }
      #pragma unroll
      for (int fn = 0; fn < 4; ++fn) {
        int brow = wn * 64 + fn * 16 + (lane & 15);
        int chk = ((h << 2) + (lane >> 4)) ^ (brow & 7);
        bv[fn] = *(const bf16x8*)(bsb + brow * 128 + chk * 16);
      }
      #pragma unroll
      for (int fm = 0; fm < 4; ++fm)
        #pragma unroll
        for (int fn = 0; fn < 4; ++fn)
          acc[fm][fn] = __builtin_amdgcn_mfma_f32_16x16x32_bf16(
              av[fm], bv[fn], acc[fm][fn], 0, 0, 0);
    }
    __syncthreads();   // readers done before next overwrite
  }

  // Epilogue: scale + bias, transpose via LDS slab [128m][17], write NCHW.
  float* slab = (float*)As;
  #pragma unroll
  for (int s = 0; s < 8; ++s) {
    if (wn == (s >> 2)) {
      const int sfn = s & 3;
      int ocol = lane & 15;
      int og = o0 + s * 16 + ocol;
      float bo = bias[og];
      #pragma unroll
      for (int fm = 0; fm < 4; ++fm) {
        #pragma unroll
        for (int j = 0; j < 4; ++j) {
          int lm = wm * 64 + fm * 16 + ((lane >> 4) << 2) + j;
          int m = m0 + lm;
          float v = acc[fm][sfn][j];
          if (m < NM) {
            int b = m / SPI;
            v = v * dco[b * 256 + og] + bo;
          }
          slab[lm * 17 + ocol] = v;
        }
      }
    }
    __syncthreads();
    int oc2 = t >> 4;
    int og2 = o0 + s * 16 + oc2;
    #pragma unroll
    for (int p = 0; p < 8; ++p) {
      int lm = (t & 15) + p * 16;
      int m = m0 + lm;
      if (m < NM) {
        int b = m / SPI; int sp = m - b * SPI;
        y[(long)(b * 256 + og2) * SPI + sp] = slab[lm * 17 + oc2];
      }
    }
    __syncthreads();
  }
}

// ---------- filtered_lrelu: column-strip version ----------
// One block = (image, 16-output-column strip). 4 strips/image, 16384 blocks.
// Strip covers out cols [c0,c0+15]; needs t2/t3 cols [2c0,2c0+41] (42),
// t1/bufY cols [c0-4,c0+21] (26, zero-padded outside image).
// Strip-local tap algebra: for t2 col pair tc={2u,2u+1}, both read
// t1[rr][u..u+5]; tc even uses odd taps, tc odd uses even taps.
// LDS: t1[138][26]=14.3KB, t2[138][42]=23.2KB (bufY[66][26] overlays t2 head,
// t3[64][42] overlays t1). Total 37.5KB -> 4 blocks/CU, 16 waves/CU.
struct Filt { float f[12]; };

__global__ __launch_bounds__(256) void k_lrelu(
    const float* __restrict__ y, float* __restrict__ out, Filt ft) {
  __shared__ __align__(16) float t1[3588];    // [138][26]
  __shared__ __align__(16) float t2[5796];    // [138][42]
  float* bufY = t2;                           // [66][26], dead before t2 written
  float* t3 = t1;                             // [64][42], written after t1 dead
  const int t = threadIdx.x;
  const int strip = blockIdx.x & 3;
  const long img = blockIdx.x >> 2;
  const int c0 = strip * 16;
  const float* ysrc = y + img * SPI;

  // phase 1: load bufY [66][26] (cols c0-4 .. c0+21, zero outside [0,66))
  #pragma unroll
  for (int p = 0; p < 7; ++p) {
    int e = p * 256 + t;
    if (e < 1716) {
      int r = e / 26, lc = e - r * 26;
      int c = c0 - 4 + lc;
      bufY[e] = (c >= 0 && c < 66) ? ysrc[r * 66 + c] : 0.f;
    }
  }
  __syncthreads();

  // phase 2: vertical up-FIR -> t1 [138][26], column pairs (float2)
  #pragma unroll
  for (int p = 0; p < 8; ++p) {
    int e = p * 256 + t;
    if (e < 1794) {                       // 138 rows x 13 col-pairs
      int rr = e / 13, u = e - rr * 13;
      int p0 = (rr + 1) & 1;
      int yr0 = (rr + p0 - 9) >> 1;
      float a0 = 0.f, a1 = 0.f;
      #pragma unroll
      for (int j = 0; j < 6; ++j) {
        int yr = yr0 + j;
        if (yr >= 0 && yr < 66) {
          float cf = ft.f[2 * j + p0];
          float2 v = *(const float2*)&bufY[yr * 26 + 2 * u];
          a0 += cf * v.x; a1 += cf * v.y;
        }
      }
      *(float2*)&t1[rr * 26 + 2 * u] = make_float2(2.f * a0, 2.f * a1);
    }
  }
  __syncthreads();

  // phase 3: horizontal up-FIR + lrelu*sqrt2 + clamp -> t2 [138][42]
  #pragma unroll
  for (int p = 0; p < 12; ++p) {
    int e = p * 256 + t;
    if (e < 2898) {                       // 138 rows x 21 col-pairs
      int rr = e / 21, u = e - rr * 21;
      const float* trow = t1 + rr * 26 + u;
      float a0 = 0.f, a1 = 0.f;
      #pragma unroll
      for (int j = 0; j < 6; ++j) {
        float v = trow[j];
        a0 += ft.f[2 * j + 1] * v;        // tc=2u   (q0=1, odd taps)
        a1 += ft.f[2 * j] * v;            // tc=2u+1 (q0=0, even taps)
      }
      a0 *= 2.f; a1 *= 2.f;
      a0 = (a0 < 0.f ? 0.2f * a0 : a0) * 1.41421356237f;
      a1 = (a1 < 0.f ? 0.2f * a1 : a1) * 1.41421356237f;
      a0 = fminf(fmaxf(a0, -256.f), 256.f);
      a1 = fminf(fmaxf(a1, -256.f), 256.f);
      *(float2*)&t2[rr * 42 + 2 * u] = make_float2(a0, a1);
    }
  }
  __syncthreads();

  // phase 4: vertical down-FIR (stride 2) -> t3 [64][42], column pairs
  #pragma unroll
  for (int p = 0; p < 6; ++p) {
    int e = p * 256 + t;
    if (e < 1344) {                       // 64 rows x 21 col-pairs
      int pp = e / 21, u = e - pp * 21;
      const float* col = t2 + (2 * pp) * 42 + 2 * u;
      float a0 = 0.f, a1 = 0.f;
      #pragma unroll
      for (int j = 0; j < 12; ++j) {
        float2 v = *(const float2*)&col[j * 42];
        a0 += ft.f[j] * v.x; a1 += ft.f[j] * v.y;
      }
      *(float2*)&t3[pp * 42 + 2 * u] = make_float2(a0, a1);
    }
  }
  __syncthreads();

  // phase 5: horizontal down-FIR (stride 2) + store, output pairs
  #pragma unroll
  for (int p = 0; p < 2; ++p) {
    int e = p * 256 + t;                  // 64 rows x 8 out-pairs = 512
    int pp = e >> 3, u = e & 7;
    const float* row = t3 + pp * 42 + 4 * u;
    float v[14];
    #pragma unroll
    for (int j = 0; j < 14; ++j) v[j] = row[j];
    float a0 = 0.f, a1 = 0.f;
    #pragma unroll
    for (int j = 0; j < 12; ++j) { a0 += ft.f[j] * v[j]; a1 += ft.f[j] * v[j + 2]; }
    *(float2*)&out[img * 4096 + pp * 64 + c0 + 2 * u] = make_float2(a0, a1);
  }
}

// ---------- host ----------
static double bessel_i0(double x) {
  double q = x * x * 0.25, term = 1.0, sum = 1.0;
  for (int k = 1; k < 64; ++k) {
    term *= q / ((double)k * (double)k);
    sum += term;
    if (term < sum * 1e-18) break;
  }
  return sum;
}

extern "C" void kernel_launch(void* const* d_in, const int* in_sizes, int n_in,
                              void* d_out, int out_size, void* d_ws, size_t ws_size,
                              hipStream_t stream) {
  const float* x   = (const float*)d_in[0];
  const float* w   = (const float*)d_in[1];
  const float* aw  = (const float*)d_in[2];
  const float* ab  = (const float*)d_in[3];
  const float* cw  = (const float*)d_in[4];
  const float* cb  = (const float*)d_in[5];
  const float* ema = (const float*)d_in[6];
  float* out = (float*)d_out;
  char* ws = (char*)d_ws;

  float* styles        = (float*)(ws + 0);          // 16 KB
  float* scal          = (float*)(ws + 16384);      // 16 B
  float* wsq           = (float*)(ws + 16640);      // 256 KB
  float* dco           = (float*)(ws + 278784);     // 16 KB
  __hip_bfloat16* wbt  = (__hip_bfloat16*)(ws + 295168);   // 1.18 MB  [9][256][256]
  unsigned short* xp   = (unsigned short*)(ws + 1474816);  // 37.9 MB  [16][68][68][256]
  float* y             = (float*)(ws + 39354624);   // 71.4 MB  [16][256][66][66]

  // firwin(12, 16, width=32, fs=128) with Kaiser window (double precision)
  Filt ft;
  {
    double atten = 2.285 * 11.0 * M_PI * 0.5 + 7.95;
    double beta;
    if (atten > 50.0) beta = 0.1102 * (atten - 8.7);
    else if (atten > 21.0) beta = 0.5842 * pow(atten - 21.0, 0.4) + 0.07886 * (atten - 21.0);
    else beta = 0.0;
    double i0b = bessel_i0(beta);
    double h[12], ssum = 0.0;
    for (int n = 0; n < 12; ++n) {
      double xx = ((double)n - 5.5) / 5.5;
      double win = bessel_i0(beta * sqrt(1.0 - xx * xx)) / i0b;
      double mm = ((double)n - 5.5) * 0.25;
      double snc = sin(M_PI * mm) / (M_PI * mm);
      h[n] = 0.25 * snc * win;
      ssum += h[n];
    }
    for (int n = 0; n < 12; ++n) ft.f[n] = (float)(h[n] / ssum);
  }

  k_styles <<<16, 256, 0, stream>>>(w, aw, ab, styles);
  k_scalars<<<1, 256, 0, stream>>>(styles, ema, scal);
  k_wnorm  <<<256, 256, 0, stream>>>(cw, wsq, wbt);
  k_dcoefs <<<16, 256, 0, stream>>>(styles, wsq, scal, dco);
  k_xpad   <<<dim3(4, 68, 16), 256, 0, stream>>>(x, styles, scal, xp);
  k_conv   <<<dim3(2, 545), 256, 0, stream>>>(xp, (const unsigned short*)wbt, dco, cb, y);
  k_lrelu  <<<16384, 256, 0, stream>>>(y, out, ft);
}